// Round 4
// baseline (231.770 us; speedup 1.0000x reference)
//
#include <hip/hip_runtime.h>
#include <stdint.h>

#define TOKENS 8192
#define EDIM 512
#define HNUM 8
#define RNUM 16
#define DDIM 64
#define KDIM 512

typedef short v8s __attribute__((ext_vector_type(8)));
typedef float v4f __attribute__((ext_vector_type(4)));

__device__ inline float b2f(unsigned short u) {
    union { unsigned int i; float f; } c; c.i = ((unsigned int)u) << 16; return c.f;
}
__device__ inline unsigned short f2b(float f) {
    union { float f; unsigned int i; } c; c.f = f;
    unsigned int i = c.i + 0x7fffu + ((c.i >> 16) & 1u);
    return (unsigned short)(i >> 16);
}

// async global->LDS, 16B per lane; LDS dest = wave-uniform base + lane*16
#define GLD16(dst, src) \
    __builtin_amdgcn_global_load_lds((__attribute__((address_space(1))) void*)(src), \
                                     (__attribute__((address_space(3))) void*)(dst), 16, 0, 0)

// ---- fp32 -> bf16 convert, 5 segments in one launch (blockIdx.y picks) ----
__global__ __launch_bounds__(256)
void cvt5(const float* __restrict__ s0, const float* __restrict__ s1,
          const float* __restrict__ s2, const float* __restrict__ s3,
          const float* __restrict__ s4,
          unsigned short* __restrict__ d0, unsigned short* __restrict__ d1,
          unsigned short* __restrict__ d2, unsigned short* __restrict__ d3,
          unsigned short* __restrict__ d4,
          int n0, int n1, int n2, int n3, int n4)
{
    const float* s; unsigned short* d; int n;
    switch (blockIdx.y) {
        case 0: s = s0; d = d0; n = n0; break;
        case 1: s = s1; d = d1; n = n1; break;
        case 2: s = s2; d = d2; n = n2; break;
        case 3: s = s3; d = d3; n = n3; break;
        default: s = s4; d = d4; n = n4; break;
    }
    size_t base = (size_t)blockIdx.x * 2048 + (size_t)threadIdx.x * 8;
    if (base >= (size_t)n) return;
    const float4* sp = (const float4*)(s + base);
    float4 f0 = sp[0], f1 = sp[1];
    v8s o;
    o[0] = (short)f2b(f0.x); o[1] = (short)f2b(f0.y);
    o[2] = (short)f2b(f0.z); o[3] = (short)f2b(f0.w);
    o[4] = (short)f2b(f1.x); o[5] = (short)f2b(f1.y);
    o[6] = (short)f2b(f1.z); o[7] = (short)f2b(f1.w);
    *(v8s*)(d + base) = o;
}

// ---- small-GEMM path: 64x64 tiles, 1024 blocks -> 4 blocks/CU ----
// C[m,n] = sum_k A[m,k]*B[n,k]; K = 512.
// MODE 0: outH = bf16((C + bias[n]) * 0.125)   (Q projection)
// MODE 2: outF = C + bias[n]                   (O projection)
template <int MODE>
__global__ __launch_bounds__(256, 4)
void gemm64(const unsigned short* __restrict__ A,
            const unsigned short* __restrict__ B,
            const float* __restrict__ bias,
            float* __restrict__ outF,
            unsigned short* __restrict__ outH)
{
    __shared__ unsigned short As[64 * 32];
    __shared__ unsigned short Bs[64 * 32];

    const int tid  = threadIdx.x;
    const int w    = tid >> 6;
    const int lane = tid & 63;
    const int quad = lane >> 4;
    const int l16  = lane & 15;
    const int wm   = w >> 1, wn = w & 1;
    const int m0   = blockIdx.x * 64;
    const int n0   = blockIdx.y * 64;

    v4f acc[2][2];
#pragma unroll
    for (int i = 0; i < 2; ++i)
#pragma unroll
        for (int j = 0; j < 2; ++j)
            acc[i][j] = (v4f){0.f, 0.f, 0.f, 0.f};

    for (int kt = 0; kt < KDIM / 32; ++kt) {
        int c = w * 64 + lane;
        const unsigned short* sa = A + (size_t)(m0 + (c >> 2)) * KDIM + kt * 32 + (c & 3) * 8;
        GLD16(&As[w * 512], sa);
        const unsigned short* sb = B + (size_t)(n0 + (c >> 2)) * KDIM + kt * 32 + (c & 3) * 8;
        GLD16(&Bs[w * 512], sb);
        __syncthreads();

        v8s af[2], bf[2];
#pragma unroll
        for (int mt = 0; mt < 2; ++mt)
            af[mt] = *(const v8s*)&As[(wm * 32 + mt * 16 + l16) * 32 + quad * 8];
#pragma unroll
        for (int nt = 0; nt < 2; ++nt)
            bf[nt] = *(const v8s*)&Bs[(wn * 32 + nt * 16 + l16) * 32 + quad * 8];
#pragma unroll
        for (int mt = 0; mt < 2; ++mt)
#pragma unroll
            for (int nt = 0; nt < 2; ++nt)
                acc[mt][nt] = __builtin_amdgcn_mfma_f32_16x16x32_bf16(af[mt], bf[nt], acc[mt][nt], 0, 0, 0);
        __syncthreads();
    }

#pragma unroll
    for (int mt = 0; mt < 2; ++mt)
#pragma unroll
        for (int nt = 0; nt < 2; ++nt) {
            int col = n0 + wn * 32 + nt * 16 + l16;
            float bb = bias[col];
#pragma unroll
            for (int rg = 0; rg < 4; ++rg) {
                int row = m0 + wm * 32 + mt * 16 + quad * 4 + rg;
                float v = acc[mt][nt][rg] + bb;
                if (MODE == 0) outH[(size_t)row * EDIM + col] = f2b(v * 0.125f);
                else           outF[(size_t)row * EDIM + col] = v;
            }
        }
}

// ============================================================================
// V-GEMM, 256x256x(BK=32), 3-buffer LDS rotation, ONE barrier per epoch,
// 4 output tiles per block (grid 256 = 1 block/CU, persistent pipeline).
//   C[m, token] = sum_k Wv[m,k] * value[token,k];  M = N = 8192, K = 512.
//   64 epochs/block (4 n-tiles x 16 K-steps of 32), n-tile switch is seamless:
//   staging for epoch G+2 crosses tile seams (n0 advances), pipeline never
//   drains except the compiler's vmcnt wait at epilogue attn-loads (~300cy x3).
//   3-buffer rotation removes the mid-tile barrier: epoch G reads buf[G%3],
//   stages buf[(G+2)%3] (never aliases G or G+1). Reads are consumed by this
//   epoch's MFMAs (lgkm-forced) before the end barrier; first write to the
//   read slot is G+1's stage for G+3 ≡ G (mod 3), after that barrier. SAFE.
//   vmcnt: 4 GLD16/wave/epoch; end-of-epoch outstanding = {G+1,G+2} = 8
//   -> vmcnt(4) retires exactly G+1's loads; barrier makes it block-wide.
//   Swizzle (2-way free, 64B rows): phys16B-slot = rowpair*8 + slot,
//   slot = ((g<<1)|(row&1)) ^ (rowpair&7). A 16-lane fragment read (fixed g,
//   rows r..r+15) hits all 8 slots exactly 2x = free (m136). GLD16 dest stays
//   linear; lane decode: u=(l&7)^((l>>3)&7); row=2*(l>>3)+(u&1); g=u>>1.
//   XCD map: cell = 8mb x 4ng per XCD (A 2MB + B 1MB working set, L2-fits).
// ============================================================================
__device__ __forceinline__ v8s ldfrag(const unsigned short* base, int r, int g) {
    return *(const v8s*)(base + ((r >> 1) << 6) + ((((g << 1) | (r & 1)) ^ ((r >> 1) & 7)) << 3));
}

#define MEMBAR asm volatile("" ::: "memory")
#define BARX do { MEMBAR; __builtin_amdgcn_s_barrier(); MEMBAR; } while (0)
#define BARL do { MEMBAR; asm volatile("s_waitcnt lgkmcnt(0)" ::: "memory"); \
                  __builtin_amdgcn_s_barrier(); MEMBAR; } while (0)
#define WAITV(n) asm volatile("s_waitcnt vmcnt(" #n ")" ::: "memory")

// stage one 256x32 operand tile (16 KiB): wave w covers rows w*32..w*32+31
// via 2 GLD16 (16 rows each); source rows rloc, granule gidx (see decode).
#define STAGE_T(bufp, gptr, grow0, k0s) do { \
    const unsigned short* s_ = (gptr) + (size_t)((grow0) + (w << 5) + rloc) * KDIM + (k0s) + gidx * 8; \
    GLD16((bufp) + (w << 10), s_); \
    GLD16((bufp) + (w << 10) + 512, s_ + 16 * KDIM); \
} while (0)

__global__ __launch_bounds__(512, 2)
void gemm_v(const unsigned short* __restrict__ A,
            const unsigned short* __restrict__ B,
            const float* __restrict__ bias,
            unsigned short* __restrict__ outH,
            const float* __restrict__ attn)
{
    __shared__ unsigned short As3[3][8192];
    __shared__ unsigned short Bs3[3][8192];
    __shared__ unsigned short Os[4096];

    const int tid  = threadIdx.x;
    const int w    = tid >> 6;          // wave 0..7
    const int lane = tid & 63;
    const int quad = lane >> 4;
    const int l16  = lane & 15;
    const int wm   = w >> 2;            // 0..1
    const int wn   = w & 3;             // 0..3
    // staging lane decode (inverse of the rowpair swizzle, GLD16 dest linear)
    const int su   = (lane & 7) ^ ((lane >> 3) & 7);
    const int rloc = ((lane >> 3) << 1) | (su & 1);  // 0..15
    const int gidx = su >> 1;                        // 0..3

    // grid 256 = 32 mb x 8 ng (ng = group of 4 consecutive n-tiles).
    // XCD c gets cell mb in [8*(c&3),+8) x ng in [4*(c>>2),+4).
    const int c  = blockIdx.x & 7;
    const int j  = blockIdx.x >> 3;            // 0..31
    const int mb = ((c & 3) << 3) | (j & 7);   // 0..31
    const int ng = ((c >> 2) << 2) | (j >> 3); // 0..7
    const int m0  = mb << 8;
    const int n0b = ng << 10;                  // 4 tiles x 256 tokens

    v4f acc[4][4][2];
#pragma unroll
    for (int q = 0; q < 4; ++q)
#pragma unroll
        for (int mi = 0; mi < 4; ++mi)
#pragma unroll
            for (int ni = 0; ni < 2; ++ni)
                acc[q][mi][ni] = (v4f){0.f, 0.f, 0.f, 0.f};

    const int h  = m0 >> 10;
    const int d0 = (m0 >> 4) & 63;

    // ---- prologue: stage epochs 0 and 1 ----
    STAGE_T(&As3[0][0], A, m0, 0);
    STAGE_T(&Bs3[0][0], B, n0b, 0);
    STAGE_T(&As3[1][0], A, m0, 32);
    STAGE_T(&Bs3[1][0], B, n0b, 32);
    WAITV(4);                      // epoch 0 landed; epoch 1 in flight
    BARX;

    int cur = 0;                   // buffer of current epoch
#pragma unroll 1
    for (int G = 0; G < 64; ++G) {
        const unsigned short* abase = (cur == 0) ? &As3[0][0] : (cur == 1) ? &As3[1][0] : &As3[2][0];
        const unsigned short* bbase = (cur == 0) ? &Bs3[0][0] : (cur == 1) ? &Bs3[1][0] : &Bs3[2][0];

        // fragment reads (12 x ds_read_b128, 2-way free swizzle)
        v8s af[8], bf[4];
#pragma unroll
        for (int mq = 0; mq < 2; ++mq)
#pragma unroll
            for (int mi = 0; mi < 4; ++mi)
                af[mq * 4 + mi] = ldfrag(abase, mq * 128 + wm * 64 + mi * 16 + l16, quad);
#pragma unroll
        for (int nq = 0; nq < 2; ++nq)
#pragma unroll
            for (int ni = 0; ni < 2; ++ni)
                bf[nq * 2 + ni] = ldfrag(bbase, nq * 128 + wn * 32 + ni * 16 + l16, quad);

        // stage epoch G+2 (crosses n-tile seams seamlessly)
        if (G < 62) {
            const int G2  = G + 2;
            const int stg = (cur == 0) ? 2 : cur - 1;   // (cur+2)%3
            unsigned short* sa = (stg == 0) ? &As3[0][0] : (stg == 1) ? &As3[1][0] : &As3[2][0];
            unsigned short* sb = (stg == 0) ? &Bs3[0][0] : (stg == 1) ? &Bs3[1][0] : &Bs3[2][0];
            const int k0s = (G2 & 15) * 32;
            const int n0s = n0b + ((G2 >> 4) << 8);
            STAGE_T(sa, A, m0, k0s);
            STAGE_T(sb, B, n0s, k0s);
        }

        // 32 MFMA
        __builtin_amdgcn_s_setprio(1);
#pragma unroll
        for (int mq = 0; mq < 2; ++mq)
#pragma unroll
            for (int nq = 0; nq < 2; ++nq)
#pragma unroll
                for (int mi = 0; mi < 4; ++mi)
#pragma unroll
                    for (int ni = 0; ni < 2; ++ni)
                        acc[mq * 2 + nq][mi][ni] = __builtin_amdgcn_mfma_f32_16x16x32_bf16(
                            af[mq * 4 + mi], bf[nq * 2 + ni], acc[mq * 2 + nq][mi][ni], 0, 0, 0);
        __builtin_amdgcn_s_setprio(0);

        if (G < 62) { WAITV(4); } else { WAITV(0); }   // epoch G+1 landed
        BARX;

        // ---- per-tile epilogue: rule contraction + scrambled out1 store ----
        if ((G & 15) == 15) {
            const int n0t = n0b + ((G >> 4) << 8);
#pragma unroll
            for (int mq = 0; mq < 2; ++mq)
#pragma unroll
                for (int nq = 0; nq < 2; ++nq)
#pragma unroll
                    for (int mi = 0; mi < 4; ++mi) {
                        float4 bias4 = *(const float4*)&bias[m0 + mq * 128 + wm * 64 + mi * 16 + quad * 4];
#pragma unroll
                        for (int ni = 0; ni < 2; ++ni) {
                            int tloc  = nq * 128 + wn * 32 + ni * 16 + l16;
                            float4 av = *(const float4*)&attn[(size_t)(n0t + tloc) * (HNUM * RNUM) + h * RNUM + quad * 4];
                            v4f a = acc[mq * 2 + nq][mi][ni];
                            float val = (a[0] + bias4.x) * av.x + (a[1] + bias4.y) * av.y
                                      + (a[2] + bias4.z) * av.z + (a[3] + bias4.w) * av.w;
                            val += __shfl_xor(val, 16);
                            val += __shfl_xor(val, 32);
                            if (quad == 0)
                                Os[tloc * 16 + (mq * 8 + wm * 4 + mi)] = f2b(val * 0.125f);
                        }
                    }
            BARL;   // lgkm-only barrier: does NOT drain in-flight prefetch
            {
                int tl = tid >> 1, hf = tid & 1;
                int sg = n0t + tl;
                int g  = (sg >> 11) * 2048 + h * 256 + ((sg & 2047) >> 3);
                int jx = (sg & 7) * 64 + d0 + hf * 8;
                *(v8s*)&outH[(size_t)g * EDIM + jx] = *(const v8s*)&Os[tl * 16 + hf * 8];
            }
            if (G < 63) {
#pragma unroll
                for (int q = 0; q < 4; ++q)
#pragma unroll
                    for (int mi = 0; mi < 4; ++mi)
#pragma unroll
                        for (int ni = 0; ni < 2; ++ni)
                            acc[q][mi][ni] = (v4f){0.f, 0.f, 0.f, 0.f};
            }
        }
        cur = (cur == 2) ? 0 : cur + 1;
    }
}

// per (token, head): z_r = -0.5*mean_d(((q-k)/w)^2), softmax over 16 rules.
// grid (TOKENS/16, HNUM), block 256 = 16 tokens x 16 rules.
#define RST 72   // padded LDS row stride (floats)
__global__ __launch_bounds__(256)
void rules_softmax(const unsigned short* __restrict__ q,  // bf16 (8192 x 512)
                   const float* __restrict__ rk,
                   const float* __restrict__ rw,
                   float* __restrict__ attn)
{
    __shared__ float ql[16 * RST];
    __shared__ float rkl[16 * RST];
    __shared__ float iwl[16 * RST];
    const int h   = blockIdx.y;
    const int t0  = blockIdx.x * 16;
    const int tid = threadIdx.x;

#pragma unroll
    for (int i = 0; i < 4; ++i) {
        int jj = tid + i * 256;
        int r = jj >> 6, d = jj & 63;
        rkl[r * RST + d] = rk[h * (RNUM * DDIM) + jj];
        float wv = rw[h * (RNUM * DDIM) + jj];
        iwl[r * RST + d] = 1.0f / (wv * wv);
    }
    {
        int jj = tid * 4;
        int row = jj >> 6, d = jj & 63;
        const unsigned short* src = q + (size_t)(t0 + row) * EDIM + h * DDIM + d;
        unsigned short u0 = src[0], u1 = src[1], u2 = src[2], u3 = src[3];
        ql[row * RST + d + 0] = b2f(u0);
        ql[row * RST + d + 1] = b2f(u1);
        ql[row * RST + d + 2] = b2f(u2);
        ql[row * RST + d + 3] = b2f(u3);
    }
    __syncthreads();

    const int tl = tid >> 4;
    const int r  = tid & 15;
    const float* qrow = &ql[tl * RST];
    const float* krow = &rkl[r * RST];
    const float* wrow = &iwl[r * RST];
    float z = 0.f;
#pragma unroll
    for (int d4 = 0; d4 < 16; ++d4) {
        float4 qv = *(const float4*)&qrow[d4 * 4];
        float4 kv = *(const float4*)&krow[d4 * 4];
        float4 wv = *(const float4*)&wrow[d4 * 4];
        float a0 = qv.x - kv.x; z += a0 * a0 * wv.x;
        float a1 = qv.y - kv.y; z += a1 * a1 * wv.y;
        float a2 = qv.z - kv.z; z += a2 * a2 * wv.z;
        float a3 = qv.w - kv.w; z += a3 * a3 * wv.w;
    }
    z *= (-0.5f / 64.f);
    float mx = z;
#pragma unroll
    for (int s = 1; s < 16; s <<= 1) mx = fmaxf(mx, __shfl_xor(mx, s));
    float e = __expf(z - mx);
    float sum = e;
#pragma unroll
    for (int s = 1; s < 16; s <<= 1) sum += __shfl_xor(sum, s);
    attn[(size_t)(t0 + tl) * (HNUM * RNUM) + h * RNUM + r] = e / sum;
}

extern "C" void kernel_launch(void* const* d_in, const int* in_sizes, int n_in,
                              void* d_out, int out_size, void* d_ws, size_t ws_size,
                              hipStream_t stream) {
    const float* query = (const float*)d_in[0];
    // d_in[1] = key (unused by the reference)
    const float* value = (const float*)d_in[2];
    const float* Wq = (const float*)d_in[3];
    const float* bq = (const float*)d_in[4];
    const float* Wv = (const float*)d_in[5];
    const float* bv = (const float*)d_in[6];
    const float* Wo = (const float*)d_in[7];
    const float* bo = (const float*)d_in[8];
    const float* rk = (const float*)d_in[9];
    const float* rw = (const float*)d_in[10];

    char* ws = (char*)d_ws;
    unsigned short* qbf  = (unsigned short*)(ws);                       //  8 MiB: query bf16
    unsigned short* vbf  = (unsigned short*)(ws + (size_t)( 8 << 20));  //  8 MiB: value bf16
    unsigned short* Wqb  = (unsigned short*)(ws + (size_t)(16 << 20));  // 0.5 MiB
    unsigned short* Wvb  = (unsigned short*)(ws + (size_t)(17 << 20));  //  8 MiB
    unsigned short* Wob  = (unsigned short*)(ws + (size_t)(25 << 20));  // 0.5 MiB
    unsigned short* out1 = (unsigned short*)(ws + (size_t)(26 << 20));  //  8 MiB: scrambled bf16
    unsigned short* qf   = (unsigned short*)(ws + (size_t)(34 << 20));  //  8 MiB: q bf16
    float* attn          = (float*)(ws + (size_t)(42 << 20));           //  4 MiB: attn fp32

    dim3 blk(256);
    // 0) fp32 -> bf16 conversions
    cvt5<<<dim3(2048, 5), blk, 0, stream>>>(query, value, Wv, Wq, Wo,
                                            qbf, vbf, Wvb, Wqb, Wob,
                                            TOKENS * EDIM, TOKENS * EDIM, EDIM * RNUM * EDIM,
                                            EDIM * EDIM, EDIM * EDIM);
    // 1) q = bf16((query @ Wq^T + bq) * D^-0.5)   [64x64 tiles, 1024 blocks]
    gemm64<0><<<dim3(TOKENS / 64, EDIM / 64), blk, 0, stream>>>(qbf, Wqb, bq, nullptr, qf);
    // 2) fuzzy rule attention weights
    rules_softmax<<<dim3(TOKENS / 16, HNUM), blk, 0, stream>>>(qf, rk, rw, attn);
    // 3) V-GEMM + rule contraction [256 persistent blocks, 3-buf, 4 tiles ea.]
    gemm_v<<<dim3(256), dim3(512), 0, stream>>>(Wvb, vbf, bv, out1, attn);
    // 4) final projection -> d_out (fp32)  [64x64 tiles, 1024 blocks]
    gemm64<2><<<dim3(TOKENS / 64, EDIM / 64), blk, 0, stream>>>(out1, Wob, bo, (float*)d_out, nullptr);
}

// Round 5
// 226.231 us; speedup vs baseline: 1.0245x; 1.0245x over previous
//
#include <hip/hip_runtime.h>
#include <stdint.h>

#define TOKENS 8192
#define EDIM 512
#define HNUM 8
#define RNUM 16
#define DDIM 64
#define KDIM 512

typedef short v8s __attribute__((ext_vector_type(8)));
typedef float v4f __attribute__((ext_vector_type(4)));

__device__ inline float b2f(unsigned short u) {
    union { unsigned int i; float f; } c; c.i = ((unsigned int)u) << 16; return c.f;
}
__device__ inline unsigned short f2b(float f) {
    union { float f; unsigned int i; } c; c.f = f;
    unsigned int i = c.i + 0x7fffu + ((c.i >> 16) & 1u);
    return (unsigned short)(i >> 16);
}

// async global->LDS, 16B per lane; LDS dest = wave-uniform base + lane*16
#define GLD16(dst, src) \
    __builtin_amdgcn_global_load_lds((__attribute__((address_space(1))) void*)(src), \
                                     (__attribute__((address_space(3))) void*)(dst), 16, 0, 0)

// ---- fp32 -> bf16 convert, 5 segments in one launch (blockIdx.y picks) ----
__global__ __launch_bounds__(256)
void cvt5(const float* __restrict__ s0, const float* __restrict__ s1,
          const float* __restrict__ s2, const float* __restrict__ s3,
          const float* __restrict__ s4,
          unsigned short* __restrict__ d0, unsigned short* __restrict__ d1,
          unsigned short* __restrict__ d2, unsigned short* __restrict__ d3,
          unsigned short* __restrict__ d4,
          int n0, int n1, int n2, int n3, int n4)
{
    const float* s; unsigned short* d; int n;
    switch (blockIdx.y) {
        case 0: s = s0; d = d0; n = n0; break;
        case 1: s = s1; d = d1; n = n1; break;
        case 2: s = s2; d = d2; n = n2; break;
        case 3: s = s3; d = d3; n = n3; break;
        default: s = s4; d = d4; n = n4; break;
    }
    size_t base = (size_t)blockIdx.x * 2048 + (size_t)threadIdx.x * 8;
    if (base >= (size_t)n) return;
    const float4* sp = (const float4*)(s + base);
    float4 f0 = sp[0], f1 = sp[1];
    v8s o;
    o[0] = (short)f2b(f0.x); o[1] = (short)f2b(f0.y);
    o[2] = (short)f2b(f0.z); o[3] = (short)f2b(f0.w);
    o[4] = (short)f2b(f1.x); o[5] = (short)f2b(f1.y);
    o[6] = (short)f2b(f1.z); o[7] = (short)f2b(f1.w);
    *(v8s*)(d + base) = o;
}

// ---- small-GEMM path: 64x64 tiles, 1024 blocks -> 4 blocks/CU ----
// C[m,n] = sum_k A[m,k]*B[n,k]; K = 512.
// MODE 0: outH = bf16((C + bias[n]) * 0.125)   (Q projection)
// MODE 2: outF = C + bias[n]                   (O projection)
template <int MODE>
__global__ __launch_bounds__(256, 4)
void gemm64(const unsigned short* __restrict__ A,
            const unsigned short* __restrict__ B,
            const float* __restrict__ bias,
            float* __restrict__ outF,
            unsigned short* __restrict__ outH)
{
    __shared__ unsigned short As[64 * 32];
    __shared__ unsigned short Bs[64 * 32];

    const int tid  = threadIdx.x;
    const int w    = tid >> 6;
    const int lane = tid & 63;
    const int quad = lane >> 4;
    const int l16  = lane & 15;
    const int wm   = w >> 1, wn = w & 1;
    const int m0   = blockIdx.x * 64;
    const int n0   = blockIdx.y * 64;

    v4f acc[2][2];
#pragma unroll
    for (int i = 0; i < 2; ++i)
#pragma unroll
        for (int j = 0; j < 2; ++j)
            acc[i][j] = (v4f){0.f, 0.f, 0.f, 0.f};

    for (int kt = 0; kt < KDIM / 32; ++kt) {
        int c = w * 64 + lane;
        const unsigned short* sa = A + (size_t)(m0 + (c >> 2)) * KDIM + kt * 32 + (c & 3) * 8;
        GLD16(&As[w * 512], sa);
        const unsigned short* sb = B + (size_t)(n0 + (c >> 2)) * KDIM + kt * 32 + (c & 3) * 8;
        GLD16(&Bs[w * 512], sb);
        __syncthreads();

        v8s af[2], bf[2];
#pragma unroll
        for (int mt = 0; mt < 2; ++mt)
            af[mt] = *(const v8s*)&As[(wm * 32 + mt * 16 + l16) * 32 + quad * 8];
#pragma unroll
        for (int nt = 0; nt < 2; ++nt)
            bf[nt] = *(const v8s*)&Bs[(wn * 32 + nt * 16 + l16) * 32 + quad * 8];
#pragma unroll
        for (int mt = 0; mt < 2; ++mt)
#pragma unroll
            for (int nt = 0; nt < 2; ++nt)
                acc[mt][nt] = __builtin_amdgcn_mfma_f32_16x16x32_bf16(af[mt], bf[nt], acc[mt][nt], 0, 0, 0);
        __syncthreads();
    }

#pragma unroll
    for (int mt = 0; mt < 2; ++mt)
#pragma unroll
        for (int nt = 0; nt < 2; ++nt) {
            int col = n0 + wn * 32 + nt * 16 + l16;
            float bb = bias[col];
#pragma unroll
            for (int rg = 0; rg < 4; ++rg) {
                int row = m0 + wm * 32 + mt * 16 + quad * 4 + rg;
                float v = acc[mt][nt][rg] + bb;
                if (MODE == 0) outH[(size_t)row * EDIM + col] = f2b(v * 0.125f);
                else           outF[(size_t)row * EDIM + col] = v;
            }
        }
}

// ============================================================================
// V-GEMM, 256x256x(BK=32), 3-buffer LDS rotation, ONE barrier per epoch,
// 4 output tiles per block (grid 256 = 1 block/CU, persistent pipeline).
//   ROUND-5 FIX: the round-4 swizzle slot=((g<<1)|(row&1))^(rowpair&7) made
//   each consecutive-8-lane group of a ds_read_b128 hit only 4 of the 8 16B
//   slots (rowpair = l>>1 spans just 0..3) -> 2-way conflict on EVERY
//   fragment read (SQ_LDS_BANK_CONFLICT 786K -> 7.08M, dur 83 -> 91 us).
//   HW model (validated by m201's st_16x32 data + round3-vs-4 A/B): b128
//   reads process ~8 consecutive lanes per phase; conflict-free iff each
//   8-lane group covers all 8 slots of a 128B line.
//   New slot: slot = (((row&1)<<2)|g) ^ ((row>>1)&7).
//     Fragment read (fixed g, rows r0+l16, r0 % 16 == 0): lanes 0-7 have
//     p=(l>>1)&7 in 0..3 -> slots {g^p} u {(4+g)^p} = all 8; lanes 8-15
//     p in 4..7 -> all 8.  CONFLICT-FREE.  Bijective per rowpair.
//   Staging decode (GLD16 dest linear, rule #21): lane l writes slot l&7 of
//   rowpair p with p&7 = l>>3  =>  su=(l&7)^(l>>3); row=2*(l>>3)+(su>>2);
//   g=su&3. Verified: read-back slot = su^(l>>3) = l&7.
//   Everything else identical to round 4 (structure frozen for this A/B):
//   3-buf rotation, 1 barrier/epoch, vmcnt(4), 4 n-tiles/block, XCD cells.
// ============================================================================
__device__ __forceinline__ v8s ldfrag(const unsigned short* base, int r, int g) {
    return *(const v8s*)(base + ((r >> 1) << 6) + ((((((r & 1) << 2)) | g) ^ ((r >> 1) & 7)) << 3));
}

#define MEMBAR asm volatile("" ::: "memory")
#define BARX do { MEMBAR; __builtin_amdgcn_s_barrier(); MEMBAR; } while (0)
#define BARL do { MEMBAR; asm volatile("s_waitcnt lgkmcnt(0)" ::: "memory"); \
                  __builtin_amdgcn_s_barrier(); MEMBAR; } while (0)
#define WAITV(n) asm volatile("s_waitcnt vmcnt(" #n ")" ::: "memory")

// stage one 256x32 operand tile (16 KiB): wave w covers rows w*32..w*32+31
// via 2 GLD16 (16 rows each); source row rloc, granule gidx (see decode).
#define STAGE_T(bufp, gptr, grow0, k0s) do { \
    const unsigned short* s_ = (gptr) + (size_t)((grow0) + (w << 5) + rloc) * KDIM + (k0s) + gidx * 8; \
    GLD16((bufp) + (w << 10), s_); \
    GLD16((bufp) + (w << 10) + 512, s_ + 16 * KDIM); \
} while (0)

__global__ __launch_bounds__(512, 2)
void gemm_v(const unsigned short* __restrict__ A,
            const unsigned short* __restrict__ B,
            const float* __restrict__ bias,
            unsigned short* __restrict__ outH,
            const float* __restrict__ attn)
{
    __shared__ unsigned short As3[3][8192];
    __shared__ unsigned short Bs3[3][8192];
    __shared__ unsigned short Os[4096];

    const int tid  = threadIdx.x;
    const int w    = tid >> 6;          // wave 0..7
    const int lane = tid & 63;
    const int quad = lane >> 4;
    const int l16  = lane & 15;
    const int wm   = w >> 2;            // 0..1
    const int wn   = w & 3;             // 0..3
    // staging lane decode (inverse of the slot swizzle, GLD16 dest linear)
    const int su   = (lane & 7) ^ ((lane >> 3) & 7);
    const int rloc = ((lane >> 3) << 1) | (su >> 2);  // 0..15
    const int gidx = su & 3;                          // 0..3

    // grid 256 = 32 mb x 8 ng (ng = group of 4 consecutive n-tiles).
    // XCD c gets cell mb in [8*(c&3),+8) x ng in [4*(c>>2),+4).
    const int c  = blockIdx.x & 7;
    const int j  = blockIdx.x >> 3;            // 0..31
    const int mb = ((c & 3) << 3) | (j & 7);   // 0..31
    const int ng = ((c >> 2) << 2) | (j >> 3); // 0..7
    const int m0  = mb << 8;
    const int n0b = ng << 10;                  // 4 tiles x 256 tokens

    v4f acc[4][4][2];
#pragma unroll
    for (int q = 0; q < 4; ++q)
#pragma unroll
        for (int mi = 0; mi < 4; ++mi)
#pragma unroll
            for (int ni = 0; ni < 2; ++ni)
                acc[q][mi][ni] = (v4f){0.f, 0.f, 0.f, 0.f};

    const int h  = m0 >> 10;
    const int d0 = (m0 >> 4) & 63;

    // ---- prologue: stage epochs 0 and 1 ----
    STAGE_T(&As3[0][0], A, m0, 0);
    STAGE_T(&Bs3[0][0], B, n0b, 0);
    STAGE_T(&As3[1][0], A, m0, 32);
    STAGE_T(&Bs3[1][0], B, n0b, 32);
    WAITV(4);                      // epoch 0 landed; epoch 1 in flight
    BARX;

    int cur = 0;                   // buffer of current epoch
#pragma unroll 1
    for (int G = 0; G < 64; ++G) {
        const unsigned short* abase = (cur == 0) ? &As3[0][0] : (cur == 1) ? &As3[1][0] : &As3[2][0];
        const unsigned short* bbase = (cur == 0) ? &Bs3[0][0] : (cur == 1) ? &Bs3[1][0] : &Bs3[2][0];

        // fragment reads (12 x ds_read_b128, conflict-free swizzle)
        v8s af[8], bf[4];
#pragma unroll
        for (int mq = 0; mq < 2; ++mq)
#pragma unroll
            for (int mi = 0; mi < 4; ++mi)
                af[mq * 4 + mi] = ldfrag(abase, mq * 128 + wm * 64 + mi * 16 + l16, quad);
#pragma unroll
        for (int nq = 0; nq < 2; ++nq)
#pragma unroll
            for (int ni = 0; ni < 2; ++ni)
                bf[nq * 2 + ni] = ldfrag(bbase, nq * 128 + wn * 32 + ni * 16 + l16, quad);

        // stage epoch G+2 (crosses n-tile seams seamlessly)
        if (G < 62) {
            const int G2  = G + 2;
            const int stg = (cur == 0) ? 2 : cur - 1;   // (cur+2)%3
            unsigned short* sa = (stg == 0) ? &As3[0][0] : (stg == 1) ? &As3[1][0] : &As3[2][0];
            unsigned short* sb = (stg == 0) ? &Bs3[0][0] : (stg == 1) ? &Bs3[1][0] : &Bs3[2][0];
            const int k0s = (G2 & 15) * 32;
            const int n0s = n0b + ((G2 >> 4) << 8);
            STAGE_T(sa, A, m0, k0s);
            STAGE_T(sb, B, n0s, k0s);
        }

        // 32 MFMA
        __builtin_amdgcn_s_setprio(1);
#pragma unroll
        for (int mq = 0; mq < 2; ++mq)
#pragma unroll
            for (int nq = 0; nq < 2; ++nq)
#pragma unroll
                for (int mi = 0; mi < 4; ++mi)
#pragma unroll
                    for (int ni = 0; ni < 2; ++ni)
                        acc[mq * 2 + nq][mi][ni] = __builtin_amdgcn_mfma_f32_16x16x32_bf16(
                            af[mq * 4 + mi], bf[nq * 2 + ni], acc[mq * 2 + nq][mi][ni], 0, 0, 0);
        __builtin_amdgcn_s_setprio(0);

        if (G < 62) { WAITV(4); } else { WAITV(0); }   // epoch G+1 landed
        BARX;

        // ---- per-tile epilogue: rule contraction + scrambled out1 store ----
        if ((G & 15) == 15) {
            const int n0t = n0b + ((G >> 4) << 8);
#pragma unroll
            for (int mq = 0; mq < 2; ++mq)
#pragma unroll
                for (int nq = 0; nq < 2; ++nq)
#pragma unroll
                    for (int mi = 0; mi < 4; ++mi) {
                        float4 bias4 = *(const float4*)&bias[m0 + mq * 128 + wm * 64 + mi * 16 + quad * 4];
#pragma unroll
                        for (int ni = 0; ni < 2; ++ni) {
                            int tloc  = nq * 128 + wn * 32 + ni * 16 + l16;
                            float4 av = *(const float4*)&attn[(size_t)(n0t + tloc) * (HNUM * RNUM) + h * RNUM + quad * 4];
                            v4f a = acc[mq * 2 + nq][mi][ni];
                            float val = (a[0] + bias4.x) * av.x + (a[1] + bias4.y) * av.y
                                      + (a[2] + bias4.z) * av.z + (a[3] + bias4.w) * av.w;
                            val += __shfl_xor(val, 16);
                            val += __shfl_xor(val, 32);
                            if (quad == 0)
                                Os[tloc * 16 + (mq * 8 + wm * 4 + mi)] = f2b(val * 0.125f);
                        }
                    }
            BARL;   // lgkm-only barrier: does NOT drain in-flight prefetch
            {
                int tl = tid >> 1, hf = tid & 1;
                int sg = n0t + tl;
                int g  = (sg >> 11) * 2048 + h * 256 + ((sg & 2047) >> 3);
                int jx = (sg & 7) * 64 + d0 + hf * 8;
                *(v8s*)&outH[(size_t)g * EDIM + jx] = *(const v8s*)&Os[tl * 16 + hf * 8];
            }
            if (G < 63) {
#pragma unroll
                for (int q = 0; q < 4; ++q)
#pragma unroll
                    for (int mi = 0; mi < 4; ++mi)
#pragma unroll
                        for (int ni = 0; ni < 2; ++ni)
                            acc[q][mi][ni] = (v4f){0.f, 0.f, 0.f, 0.f};
            }
        }
        cur = (cur == 2) ? 0 : cur + 1;
    }
}

// per (token, head): z_r = -0.5*mean_d(((q-k)/w)^2), softmax over 16 rules.
// grid (TOKENS/16, HNUM), block 256 = 16 tokens x 16 rules.
#define RST 72   // padded LDS row stride (floats)
__global__ __launch_bounds__(256)
void rules_softmax(const unsigned short* __restrict__ q,  // bf16 (8192 x 512)
                   const float* __restrict__ rk,
                   const float* __restrict__ rw,
                   float* __restrict__ attn)
{
    __shared__ float ql[16 * RST];
    __shared__ float rkl[16 * RST];
    __shared__ float iwl[16 * RST];
    const int h   = blockIdx.y;
    const int t0  = blockIdx.x * 16;
    const int tid = threadIdx.x;

#pragma unroll
    for (int i = 0; i < 4; ++i) {
        int jj = tid + i * 256;
        int r = jj >> 6, d = jj & 63;
        rkl[r * RST + d] = rk[h * (RNUM * DDIM) + jj];
        float wv = rw[h * (RNUM * DDIM) + jj];
        iwl[r * RST + d] = 1.0f / (wv * wv);
    }
    {
        int jj = tid * 4;
        int row = jj >> 6, d = jj & 63;
        const unsigned short* src = q + (size_t)(t0 + row) * EDIM + h * DDIM + d;
        unsigned short u0 = src[0], u1 = src[1], u2 = src[2], u3 = src[3];
        ql[row * RST + d + 0] = b2f(u0);
        ql[row * RST + d + 1] = b2f(u1);
        ql[row * RST + d + 2] = b2f(u2);
        ql[row * RST + d + 3] = b2f(u3);
    }
    __syncthreads();

    const int tl = tid >> 4;
    const int r  = tid & 15;
    const float* qrow = &ql[tl * RST];
    const float* krow = &rkl[r * RST];
    const float* wrow = &iwl[r * RST];
    float z = 0.f;
#pragma unroll
    for (int d4 = 0; d4 < 16; ++d4) {
        float4 qv = *(const float4*)&qrow[d4 * 4];
        float4 kv = *(const float4*)&krow[d4 * 4];
        float4 wv = *(const float4*)&wrow[d4 * 4];
        float a0 = qv.x - kv.x; z += a0 * a0 * wv.x;
        float a1 = qv.y - kv.y; z += a1 * a1 * wv.y;
        float a2 = qv.z - kv.z; z += a2 * a2 * wv.z;
        float a3 = qv.w - kv.w; z += a3 * a3 * wv.w;
    }
    z *= (-0.5f / 64.f);
    float mx = z;
#pragma unroll
    for (int s = 1; s < 16; s <<= 1) mx = fmaxf(mx, __shfl_xor(mx, s));
    float e = __expf(z - mx);
    float sum = e;
#pragma unroll
    for (int s = 1; s < 16; s <<= 1) sum += __shfl_xor(sum, s);
    attn[(size_t)(t0 + tl) * (HNUM * RNUM) + h * RNUM + r] = e / sum;
}

extern "C" void kernel_launch(void* const* d_in, const int* in_sizes, int n_in,
                              void* d_out, int out_size, void* d_ws, size_t ws_size,
                              hipStream_t stream) {
    const float* query = (const float*)d_in[0];
    // d_in[1] = key (unused by the reference)
    const float* value = (const float*)d_in[2];
    const float* Wq = (const float*)d_in[3];
    const float* bq = (const float*)d_in[4];
    const float* Wv = (const float*)d_in[5];
    const float* bv = (const float*)d_in[6];
    const float* Wo = (const float*)d_in[7];
    const float* bo = (const float*)d_in[8];
    const float* rk = (const float*)d_in[9];
    const float* rw = (const float*)d_in[10];

    char* ws = (char*)d_ws;
    unsigned short* qbf  = (unsigned short*)(ws);                       //  8 MiB: query bf16
    unsigned short* vbf  = (unsigned short*)(ws + (size_t)( 8 << 20));  //  8 MiB: value bf16
    unsigned short* Wqb  = (unsigned short*)(ws + (size_t)(16 << 20));  // 0.5 MiB
    unsigned short* Wvb  = (unsigned short*)(ws + (size_t)(17 << 20));  //  8 MiB
    unsigned short* Wob  = (unsigned short*)(ws + (size_t)(25 << 20));  // 0.5 MiB
    unsigned short* out1 = (unsigned short*)(ws + (size_t)(26 << 20));  //  8 MiB: scrambled bf16
    unsigned short* qf   = (unsigned short*)(ws + (size_t)(34 << 20));  //  8 MiB: q bf16
    float* attn          = (float*)(ws + (size_t)(42 << 20));           //  4 MiB: attn fp32

    dim3 blk(256);
    // 0) fp32 -> bf16 conversions
    cvt5<<<dim3(2048, 5), blk, 0, stream>>>(query, value, Wv, Wq, Wo,
                                            qbf, vbf, Wvb, Wqb, Wob,
                                            TOKENS * EDIM, TOKENS * EDIM, EDIM * RNUM * EDIM,
                                            EDIM * EDIM, EDIM * EDIM);
    // 1) q = bf16((query @ Wq^T + bq) * D^-0.5)   [64x64 tiles, 1024 blocks]
    gemm64<0><<<dim3(TOKENS / 64, EDIM / 64), blk, 0, stream>>>(qbf, Wqb, bq, nullptr, qf);
    // 2) fuzzy rule attention weights
    rules_softmax<<<dim3(TOKENS / 16, HNUM), blk, 0, stream>>>(qf, rk, rw, attn);
    // 3) V-GEMM + rule contraction [256 persistent blocks, 3-buf, 4 tiles ea.]
    gemm_v<<<dim3(256), dim3(512), 0, stream>>>(Wvb, vbf, bv, out1, attn);
    // 4) final projection -> d_out (fp32)  [64x64 tiles, 1024 blocks]
    gemm64<2><<<dim3(TOKENS / 64, EDIM / 64), blk, 0, stream>>>(out1, Wob, bo, (float*)d_out, nullptr);
}